// Round 7
// baseline (199.227 us; speedup 1.0000x reference)
//
#include <hip/hip_runtime.h>
#include <hip/hip_bf16.h>

#define NRES 320
#define CZ 128
#define NH 4
#define CH 32
#define DM 128
#define NPOS (NRES*NRES)
#define LN_EPS 1e-5f
#define QSCALE 0.17677669529663687f
#define LOG2E 1.4426950408889634f

using bf16 = __hip_bfloat16;
typedef __attribute__((ext_vector_type(8))) short short8;
typedef __attribute__((ext_vector_type(4))) float floatx4;

__device__ __forceinline__ float bflo(uint32_t u){ return __uint_as_float(u << 16); }
__device__ __forceinline__ float bfhi(uint32_t u){ return __uint_as_float(u & 0xffff0000u); }
__device__ __forceinline__ bf16 tob(float f){ return __float2bfloat16(f); }
// HW packed f32->bf16 (RNE): dst.lo = bf16(a), dst.hi = bf16(b)
__device__ __forceinline__ uint32_t cvtpk(float a, float b){
    uint32_t r;
    asm("v_cvt_pk_bf16_f32 %0, %1, %2" : "=v"(r) : "v"(a), "v"(b));
    return r;
}

// ---------- pack QKVG weights (hi+lo) into MFMA A-fragment order ----------
// Apk[wid(8)][mf(4)][ks(4)][lane(64)][j(8)]; A[e][k] = W(e>>7)[e&127][k]
// wq pre-scaled by QSCALE*LOG2E (softmax in log2 domain).
__global__ __launch_bounds__(256)
void k_packw(const float* __restrict__ wq, const float* __restrict__ wk,
             const float* __restrict__ wv, const float* __restrict__ wg,
             bf16* __restrict__ Apkh, bf16* __restrict__ Apkl)
{
    const int idx = blockIdx.x * 256 + threadIdx.x;          // 0..65535
    const int j = idx & 7, lane = (idx >> 3) & 63;
    const int ks = (idx >> 9) & 3, mf = (idx >> 11) & 3, wid = idx >> 13;
    const int e = wid*64 + mf*16 + (lane & 15);
    const int k = ks*32 + (lane >> 4)*8 + j;
    const float* w = (e >> 7) == 0 ? wq : (e >> 7) == 1 ? wk : (e >> 7) == 2 ? wv : wg;
    float wv_ = w[(e & 127)*CZ + k];
    if (e < 128) wv_ *= QSCALE * LOG2E;
    const bf16 hb = tob(wv_);
    Apkh[idx] = hb;
    Apkl[idx] = tob(wv_ - __bfloat162float(hb));
}

// ---------- pack wo (hi+lo) B-side: [wn(2)][ks(4)][nr(4)][lane(64)][j(8)] ----------
__global__ __launch_bounds__(256)
void k_packwo(const float* __restrict__ wo, bf16* __restrict__ B2h,
              bf16* __restrict__ B2l)
{
    const int idx = blockIdx.x * 256 + threadIdx.x;          // 0..16383
    const int j = idx & 7, lane = (idx >> 3) & 63;
    const int nr = (idx >> 9) & 3, ks = (idx >> 11) & 3, wn = idx >> 13;
    const int n = wn*64 + nr*16 + (lane & 15);
    const int k = ks*32 + ((lane >> 4) << 3) + j;
    const float wv_ = wo[n*DM + k];
    const bf16 hb = tob(wv_);
    B2h[idx] = hb;
    B2l[idx] = tob(wv_ - __bfloat162float(hb));
}

// ---------- pack edge_bias, f32, MFMA C-layout, *LOG2E ----------
// ebpk[h][t(10)][flat(20)][mi(2)][lane(64)][r(4)]
// value = eb[h][q=16*flat+(lane&15)][k=32t+16mi+4*(lane>>4)+r]
__global__ __launch_bounds__(256)
void k_packeb(const float* __restrict__ eb, float* __restrict__ ebpk)
{
    const int idx = blockIdx.x * 256 + threadIdx.x;          // 0..409599
    const int r = idx & 3;
    const int lane = (idx >> 2) & 63;
    const int mi = (idx >> 8) & 1;
    const int flat = (idx >> 9) % 20;
    const int t = (idx / 10240) % 10;
    const int h = idx / 102400;
    const int q = flat*16 + (lane & 15);
    const int k = t*32 + mi*16 + (lane >> 4)*4 + r;
    ebpk[idx] = eb[((size_t)h*NRES + q)*NRES + k] * LOG2E;
}

// ---------- Kernel 1: LN + QKVG projection, split-bf16 MFMA (A=W, B=zn) ----------
// grid NPOS/64, block 512. Wave wid owns output e in [wid*64, wid*64+64), all 64 jj.
__global__ __launch_bounds__(512, 3)
void k_lnproj(const float* __restrict__ z, const float* __restrict__ ln_w,
              const float* __restrict__ ln_b, const bf16* __restrict__ Apkh,
              const bf16* __restrict__ Apkl,
              bf16* __restrict__ qws, bf16* __restrict__ kws,
              bf16* __restrict__ vws, bf16* __restrict__ gows)
{
    // zn tiles [64 rows][256B], 16B-slot cc swizzled: off = row*256 + ((cc)^(row&7))*16
    __shared__ __align__(16) char Ash[64 * 256];
    __shared__ __align__(16) char Asl[64 * 256];
    const int tid = threadIdx.x;
    const int p0 = blockIdx.x * 64;
    const int lane = tid & 63, wid = tid >> 6;
    const int l15 = lane & 15, g = lane >> 4;

    // LayerNorm: thread (r = tid>>3, t = tid&7) handles cols 16t..16t+15
    {
        const int r = tid >> 3, t = tid & 7, c0 = t*16;
        const float* zp = z + (size_t)(p0 + r)*CZ + c0;
        float v[16];
        {
            float4 t0 = *(const float4*)(zp + 0);
            float4 t1 = *(const float4*)(zp + 4);
            float4 t2 = *(const float4*)(zp + 8);
            float4 t3 = *(const float4*)(zp + 12);
            v[0]=t0.x; v[1]=t0.y; v[2]=t0.z; v[3]=t0.w;
            v[4]=t1.x; v[5]=t1.y; v[6]=t1.z; v[7]=t1.w;
            v[8]=t2.x; v[9]=t2.y; v[10]=t2.z; v[11]=t2.w;
            v[12]=t3.x; v[13]=t3.y; v[14]=t3.z; v[15]=t3.w;
        }
        float s = 0.f, s2 = 0.f;
        #pragma unroll
        for (int c = 0; c < 16; ++c) { s += v[c]; s2 = fmaf(v[c], v[c], s2); }
        s  += __shfl_xor(s, 1);  s  += __shfl_xor(s, 2);  s  += __shfl_xor(s, 4);
        s2 += __shfl_xor(s2, 1); s2 += __shfl_xor(s2, 2); s2 += __shfl_xor(s2, 4);
        const float mu = s * 0.0078125f;
        const float rs = rsqrtf(s2 * 0.0078125f - mu*mu + LN_EPS);
        float vn[16];
        #pragma unroll
        for (int c = 0; c < 16; ++c)
            vn[c] = (v[c] - mu) * rs * ln_w[c0 + c] + ln_b[c0 + c];
        uint32_t hd[8], ld[8];
        #pragma unroll
        for (int c2 = 0; c2 < 8; ++c2) {
            hd[c2] = cvtpk(vn[2*c2], vn[2*c2+1]);
            ld[c2] = cvtpk(vn[2*c2]   - bflo(hd[c2]),
                           vn[2*c2+1] - bfhi(hd[c2]));
        }
        const int rho = r & 7;
        const int s0 = ((2*t    ) ^ rho) * 16;
        const int s1 = ((2*t + 1) ^ rho) * 16;
        *(uint4*)(Ash + r*256 + s0) = make_uint4(hd[0], hd[1], hd[2], hd[3]);
        *(uint4*)(Ash + r*256 + s1) = make_uint4(hd[4], hd[5], hd[6], hd[7]);
        *(uint4*)(Asl + r*256 + s0) = make_uint4(ld[0], ld[1], ld[2], ld[3]);
        *(uint4*)(Asl + r*256 + s1) = make_uint4(ld[4], ld[5], ld[6], ld[7]);
    }
    __syncthreads();

    floatx4 acc[4][4];
    #pragma unroll
    for (int mf = 0; mf < 4; ++mf)
        #pragma unroll
        for (int nf = 0; nf < 4; ++nf)
            acc[mf][nf] = (floatx4){0.f, 0.f, 0.f, 0.f};

    const uint4* aph = (const uint4*)Apkh;
    const uint4* apl = (const uint4*)Apkl;
    #pragma unroll
    for (int ks = 0; ks < 4; ++ks) {
        uint4 ahv[4], alv[4];
        #pragma unroll
        for (int mf = 0; mf < 4; ++mf) {
            ahv[mf] = aph[((wid*4 + mf)*4 + ks)*64 + lane];
            alv[mf] = apl[((wid*4 + mf)*4 + ks)*64 + lane];
        }
        #pragma unroll
        for (int nf = 0; nf < 4; ++nf) {
            const int row = nf*16 + l15;
            const int off = row*256 + (((ks*4 + g) ^ (row & 7)) * 16);
            const short8 bh = *(const short8*)(Ash + off);
            const short8 bl = *(const short8*)(Asl + off);
            #pragma unroll
            for (int mf = 0; mf < 4; ++mf) {
                const short8 ah = *(const short8*)&ahv[mf];
                const short8 al = *(const short8*)&alv[mf];
                acc[mf][nf] = __builtin_amdgcn_mfma_f32_16x16x32_bf16(ah, bh, acc[mf][nf], 0, 0, 0);
                acc[mf][nf] = __builtin_amdgcn_mfma_f32_16x16x32_bf16(al, bh, acc[mf][nf], 0, 0, 0);
                acc[mf][nf] = __builtin_amdgcn_mfma_f32_16x16x32_bf16(ah, bl, acc[mf][nf], 0, 0, 0);
            }
        }
    }

    // epilogue: lane holds 4 consecutive c -> dwordx2 stores
    const int i = p0 / NRES;          // blocks never straddle i
    const int j0 = p0 % NRES;
    #pragma unroll
    for (int mf = 0; mf < 4; ++mf) {
        const int e0 = wid*64 + mf*16 + 4*g;
        const int hh = (e0 >> 5) & 3, c0 = e0 & 31;
        #pragma unroll
        for (int nf = 0; nf < 4; ++nf) {
            const int jl = nf*16 + l15;
            const floatx4 a = acc[mf][nf];
            if (wid < 6) {
                uint2 dw;
                dw.x = cvtpk(a[0], a[1]);
                dw.y = cvtpk(a[2], a[3]);
                bf16* dst = (wid < 2) ? qws : (wid < 4) ? kws : vws;
                const size_t hidx = ((size_t)((i*NH + hh)*NRES) + (j0 + jl))*CH + c0;
                *(uint2*)(dst + hidx) = dw;
            } else {
                const float g0 = 1.f / (1.f + __expf(-a[0]));
                const float g1 = 1.f / (1.f + __expf(-a[1]));
                const float g2 = 1.f / (1.f + __expf(-a[2]));
                const float g3 = 1.f / (1.f + __expf(-a[3]));
                uint2 dw;
                dw.x = cvtpk(g0, g1);
                dw.y = cvtpk(g2, g3);
                *(uint2*)(gows + (size_t)(p0 + jl)*DM + (e0 & 127)) = dw;
            }
        }
    }
}

// ---------------- Kernel 2: MFMA flash attention, grid (qq=2, i, h) ----------------
// 5 waves; wave w owns q in [160qq+32w, +32): 2 nf frags. log2-domain softmax.
// S^T = mfma(K, Q, C=eb); O^T = V^T·P^T; P via in-register shuffles.
__global__ __launch_bounds__(320, 4)
void k_attn(const bf16* __restrict__ qws, const bf16* __restrict__ kws,
            const bf16* __restrict__ vws, bf16* __restrict__ gows,
            const float* __restrict__ mask_bias, const float* __restrict__ ebpk)
{
    // K frag-linear 20KB @0 | Vt 32 rows x 688B @20480 | mb f32[320] @42496
    __shared__ __align__(16) char smem[43776];
    constexpr int KS_OFF = 0, VT_OFF = 20480, MB_OFF = 42496;
    const int qq = blockIdx.x, i = blockIdx.y, h = blockIdx.z;
    const int tid = threadIdx.x;
    const int lane = tid & 63, w = tid >> 6;
    const int l15 = lane & 15, g = lane >> 4;
    const size_t slab = (size_t)(i*NH + h) * NRES * CH;

    // K -> fragment-linear LDS
    {
        const uint4* kg = (const uint4*)(kws + slab);
        #pragma unroll
        for (int it = 0; it < 4; ++it) {
            const int idx = tid + it*320;
            const int row = idx >> 2, gc = idx & 3;
            *(uint4*)(smem + KS_OFF + (row >> 4)*1024 + (gc*16 + (row & 15))*16) = kg[idx];
        }
    }
    // V row tid -> Vt columns (688B row skew)
    {
        const uint4* vg = (const uint4*)(vws + slab) + tid*4;
        uint32_t dw[16];
        *(uint4*)&dw[0]  = vg[0];
        *(uint4*)&dw[4]  = vg[1];
        *(uint4*)&dw[8]  = vg[2];
        *(uint4*)&dw[12] = vg[3];
        #pragma unroll
        for (int c = 0; c < 32; ++c) {
            const uint32_t d = dw[c >> 1];
            const unsigned short hv = (c & 1) ? (unsigned short)(d >> 16)
                                              : (unsigned short)(d & 0xffffu);
            *(unsigned short*)(smem + VT_OFF + c*688 + tid*2) = hv;
        }
    }
    ((float*)(smem + MB_OFF))[tid] = mask_bias[(size_t)i*NRES + tid] * LOG2E;

    // Q B-frags direct from global
    short8 bq[2];
    {
        const uint4* qg = (const uint4*)(qws + slab);
        #pragma unroll
        for (int nf = 0; nf < 2; ++nf) {
            uint4 t = qg[(160*qq + 32*w + 16*nf + l15)*4 + g];
            bq[nf] = *(short8*)&t;
        }
    }
    __syncthreads();

    const floatx4* ebp = (const floatx4*)ebpk;
    const int flat0 = qq*10 + 2*w;   // + nf

    floatx4 o[2][2];
    #pragma unroll
    for (int ma = 0; ma < 2; ++ma)
        #pragma unroll
        for (int nf = 0; nf < 2; ++nf)
            o[ma][nf] = (floatx4){0.f, 0.f, 0.f, 0.f};
    float m[2] = {-1e30f, -1e30f};
    float l[2] = {0.f, 0.f};

    const int srcA = ((lane >> 4) & 1)*32 + l15;
    const int srcB = srcA + 16;
    const bool hisel = (lane & 32) != 0;

    for (int t = 0; t < 10; ++t) {
        const short8 ak0 = *(const short8*)(smem + KS_OFF + t*2048 + lane*16);
        const short8 ak1 = *(const short8*)(smem + KS_OFF + t*2048 + 1024 + lane*16);
        const short8 av0 = *(const short8*)(smem + VT_OFF + (     l15)*688 + t*64 + g*16);
        const short8 av1 = *(const short8*)(smem + VT_OFF + (16 + l15)*688 + t*64 + g*16);

        // S^T = K·Q^T with eb as C-input (f32, pre-scaled by log2e)
        floatx4 sa[2][2];
        #pragma unroll
        for (int nf = 0; nf < 2; ++nf) {
            const int bi = (((h*10 + t)*20 + flat0 + nf)*2)*64 + lane;
            const floatx4 e0 = ebp[bi];
            const floatx4 e1 = ebp[bi + 64];
            sa[0][nf] = __builtin_amdgcn_mfma_f32_16x16x32_bf16(ak0, bq[nf], e0, 0, 0, 0);
            sa[1][nf] = __builtin_amdgcn_mfma_f32_16x16x32_bf16(ak1, bq[nf], e1, 0, 0, 0);
        }
        // mask bias (broadcast LDS reads)
        float2 mbv[2][2];
        #pragma unroll
        for (int mi = 0; mi < 2; ++mi)
            #pragma unroll
            for (int rp = 0; rp < 2; ++rp)
                mbv[mi][rp] = *(const float2*)(smem + MB_OFF + (32*t + 16*mi + 4*g + 2*rp)*4);

        float sv[2][2][4];
        float lmax[2];
        #pragma unroll
        for (int nf = 0; nf < 2; ++nf) {
            #pragma unroll
            for (int mi = 0; mi < 2; ++mi) {
                sv[nf][mi][0] = sa[mi][nf][0] + mbv[mi][0].x;
                sv[nf][mi][1] = sa[mi][nf][1] + mbv[mi][0].y;
                sv[nf][mi][2] = sa[mi][nf][2] + mbv[mi][1].x;
                sv[nf][mi][3] = sa[mi][nf][3] + mbv[mi][1].y;
            }
            const float a0 = fmaxf(fmaxf(sv[nf][0][0], sv[nf][0][1]), sv[nf][0][2]);
            const float a1 = fmaxf(fmaxf(sv[nf][0][3], sv[nf][1][0]), sv[nf][1][1]);
            const float a2 = fmaxf(sv[nf][1][2], sv[nf][1][3]);
            lmax[nf] = fmaxf(fmaxf(a0, a1), a2);
        }
        const float gm = fmaxf(lmax[0] - m[0], lmax[1] - m[1]);
        if (__any(gm > 10.0f)) {
            #pragma unroll
            for (int nf = 0; nf < 2; ++nf) {
                float pm = lmax[nf];
                pm = fmaxf(pm, __shfl_xor(pm, 16));
                pm = fmaxf(pm, __shfl_xor(pm, 32));
                const float mn = fmaxf(m[nf], pm);
                const float sc = exp2f(m[nf] - mn);
                l[nf] *= sc;
                #pragma unroll
                for (int ma = 0; ma < 2; ++ma)
                    #pragma unroll
                    for (int r = 0; r < 4; ++r)
                        o[ma][nf][r] *= sc;
                m[nf] = mn;
            }
        }
        // p = 2^(s-m); pack via hw cvt_pk; C-layout -> B-frag shuffles
        short8 bp[2];
        #pragma unroll
        for (int nf = 0; nf < 2; ++nf) {
            const float p00 = exp2f(sv[nf][0][0] - m[nf]);
            const float p01 = exp2f(sv[nf][0][1] - m[nf]);
            const float p02 = exp2f(sv[nf][0][2] - m[nf]);
            const float p03 = exp2f(sv[nf][0][3] - m[nf]);
            const float p10 = exp2f(sv[nf][1][0] - m[nf]);
            const float p11 = exp2f(sv[nf][1][1] - m[nf]);
            const float p12 = exp2f(sv[nf][1][2] - m[nf]);
            const float p13 = exp2f(sv[nf][1][3] - m[nf]);
            l[nf] += ((p00 + p01) + (p02 + p03)) + ((p10 + p11) + (p12 + p13));
            const uint32_t d00 = cvtpk(p00, p01), d01 = cvtpk(p02, p03);
            const uint32_t d10 = cvtpk(p10, p11), d11 = cvtpk(p12, p13);
            const uint32_t a0 = (uint32_t)__shfl((int)d00, srcA);
            const uint32_t a1 = (uint32_t)__shfl((int)d01, srcA);
            const uint32_t a2 = (uint32_t)__shfl((int)d10, srcA);
            const uint32_t a3 = (uint32_t)__shfl((int)d11, srcA);
            const uint32_t b0 = (uint32_t)__shfl((int)d00, srcB);
            const uint32_t b1 = (uint32_t)__shfl((int)d01, srcB);
            const uint32_t b2 = (uint32_t)__shfl((int)d10, srcB);
            const uint32_t b3 = (uint32_t)__shfl((int)d11, srcB);
            uint4 u;
            u.x = hisel ? a2 : a0;
            u.y = hisel ? a3 : a1;
            u.z = hisel ? b2 : b0;
            u.w = hisel ? b3 : b1;
            bp[nf] = *(short8*)&u;
        }
        #pragma unroll
        for (int nf = 0; nf < 2; ++nf) {
            o[0][nf] = __builtin_amdgcn_mfma_f32_16x16x32_bf16(av0, bp[nf], o[0][nf], 0, 0, 0);
            o[1][nf] = __builtin_amdgcn_mfma_f32_16x16x32_bf16(av1, bp[nf], o[1][nf], 0, 0, 0);
        }
    }

    float linv[2];
    #pragma unroll
    for (int nf = 0; nf < 2; ++nf) {
        float ls = l[nf];
        ls += __shfl_xor(ls, 16);
        ls += __shfl_xor(ls, 32);
        linv[nf] = 1.f / ls;
    }
    uint32_t* gp = (uint32_t*)gows;
    #pragma unroll
    for (int nf = 0; nf < 2; ++nf) {
        const int jq = 160*qq + 32*w + 16*nf + l15;
        #pragma unroll
        for (int ma = 0; ma < 2; ++ma)
            #pragma unroll
            for (int rp = 0; rp < 2; ++rp) {
                const size_t idx = ((size_t)(i*NRES + jq))*64 + h*16 + 8*ma + 2*g + rp;
                const uint32_t u = gp[idx];
                const float v0 = o[ma][nf][2*rp    ] * linv[nf] * bflo(u);
                const float v1 = o[ma][nf][2*rp + 1] * linv[nf] * bfhi(u);
                gp[idx] = cvtpk(v0, v1);
            }
    }
}

// ---------- Kernel 3: output projection, MFMA (B split; A is bf16-exact) ----------
__global__ __launch_bounds__(512)
void k_outproj(const bf16* __restrict__ gows, const bf16* __restrict__ B2h,
               const bf16* __restrict__ B2l, float* __restrict__ out)
{
    __shared__ __align__(16) char As[256 * 256];
    const int tid = threadIdx.x;
    const int p0 = blockIdx.x * 256;
    const int lane = tid & 63, wid = tid >> 6;
    const int wm = wid >> 1, wn = wid & 1;

    short8 bh[4][4];
    {
        const uint4* bp = (const uint4*)B2h;
        #pragma unroll
        for (int ks = 0; ks < 4; ++ks)
            #pragma unroll
            for (int nr = 0; nr < 4; ++nr) {
                uint4 t = bp[(((wn*4 + ks)*4) + nr)*64 + lane];
                bh[ks][nr] = *(short8*)&t;
            }
    }

    {
        const uint4* src = (const uint4*)(gows + (size_t)p0 * DM);
        #pragma unroll
        for (int it = 0; it < 8; ++it) {
            const int t = tid + it*512;
            uint4 u = src[t];
            const int row = t >> 4, cb = (t & 15) * 16;
            *(uint4*)(As + ((row*256 + cb) ^ ((row & 7) << 4))) = u;
        }
    }
    __syncthreads();

    floatx4 acc[4][4];
    #pragma unroll
    for (int m = 0; m < 4; ++m)
        #pragma unroll
        for (int n = 0; n < 4; ++n)
            acc[m][n] = (floatx4){0.f, 0.f, 0.f, 0.f};

    const uint4* bpl = (const uint4*)B2l;
    #pragma unroll
    for (int ks = 0; ks < 4; ++ks) {
        short8 a[4];
        #pragma unroll
        for (int m = 0; m < 4; ++m) {
            const int row = wm*64 + m*16 + (lane & 15);
            const int kb = ks*64 + ((lane >> 4) << 4);
            a[m] = *(const short8*)(As + ((row*256 + kb) ^ ((row & 7) << 4)));
        }
        #pragma unroll
        for (int nr = 0; nr < 4; ++nr) {
            uint4 tl = bpl[(((wn*4 + ks)*4) + nr)*64 + lane];
            const short8 bl = *(short8*)&tl;
            #pragma unroll
            for (int m = 0; m < 4; ++m)
                acc[m][nr] = __builtin_amdgcn_mfma_f32_16x16x32_bf16(a[m], bh[ks][nr], acc[m][nr], 0, 0, 0);
            #pragma unroll
            for (int m = 0; m < 4; ++m)
                acc[m][nr] = __builtin_amdgcn_mfma_f32_16x16x32_bf16(a[m], bl, acc[m][nr], 0, 0, 0);
        }
    }

    #pragma unroll
    for (int m = 0; m < 4; ++m) {
        #pragma unroll
        for (int n = 0; n < 4; ++n) {
            const int d = wn*64 + n*16 + (lane & 15);
            #pragma unroll
            for (int r = 0; r < 4; ++r) {
                const int prow = p0 + wm*64 + m*16 + ((lane >> 4) << 2) + r;
                out[(size_t)prow*DM + d] = acc[m][n][r];
            }
        }
    }
}

extern "C" void kernel_launch(void* const* d_in, const int* in_sizes, int n_in,
                              void* d_out, int out_size, void* d_ws, size_t ws_size,
                              hipStream_t stream)
{
    const float* z   = (const float*)d_in[0];
    const float* mb  = (const float*)d_in[1];
    const float* eb  = (const float*)d_in[2];
    const float* wq  = (const float*)d_in[3];
    const float* wk  = (const float*)d_in[4];
    const float* wv  = (const float*)d_in[5];
    const float* wg  = (const float*)d_in[6];
    const float* wo  = (const float*)d_in[7];
    const float* lnw = (const float*)d_in[8];
    const float* lnb = (const float*)d_in[9];
    float* out = (float*)d_out;

    const size_t SEG = (size_t)NPOS * DM;
    bf16* qws  = (bf16*)d_ws;
    bf16* kws  = qws + SEG;
    bf16* vws  = kws + SEG;
    bf16* gows = vws + SEG;
    bf16* Apkh = gows + SEG;         // 65536
    bf16* Apkl = Apkh + 65536;       // 65536
    bf16* B2h  = Apkl + 65536;       // 16384
    bf16* B2l  = B2h + 16384;        // 16384
    float* ebpk = (float*)(B2l + 16384);   // 409600 f32 (16B-aligned)

    k_packw<<<256, 256, 0, stream>>>(wq, wk, wv, wg, Apkh, Apkl);
    k_packwo<<<64, 256, 0, stream>>>(wo, B2h, B2l);
    k_packeb<<<1600, 256, 0, stream>>>(eb, ebpk);
    k_lnproj<<<NPOS/64, 512, 0, stream>>>(z, lnw, lnb, Apkh, Apkl, qws, kws, vws, gows);
    k_attn<<<dim3(2, NRES, NH), 320, 0, stream>>>(qws, kws, vws, gows, mb, ebpk);
    k_outproj<<<NPOS/256, 512, 0, stream>>>(gows, B2h, B2l, out);
}

// Round 9
// 166.321 us; speedup vs baseline: 1.1978x; 1.1978x over previous
//
#include <hip/hip_runtime.h>
#include <hip/hip_bf16.h>

#define NRES 320
#define CZ 128
#define NH 4
#define CH 32
#define DM 128
#define NPOS (NRES*NRES)
#define LN_EPS 1e-5f
#define QSCALE 0.17677669529663687f
#define LOG2E 1.4426950408889634f

using bf16 = __hip_bfloat16;
typedef __attribute__((ext_vector_type(8))) short short8;
typedef __attribute__((ext_vector_type(4))) float floatx4;

__device__ __forceinline__ float bflo(uint32_t u){ return __uint_as_float(u << 16); }
__device__ __forceinline__ float bfhi(uint32_t u){ return __uint_as_float(u & 0xffff0000u); }
__device__ __forceinline__ bf16 tob(float f){ return __float2bfloat16(f); }
// HW packed f32->bf16 (RNE): dst.lo = bf16(a), dst.hi = bf16(b)
__device__ __forceinline__ uint32_t cvtpk(float a, float b){
    uint32_t r;
    asm("v_cvt_pk_bf16_f32 %0, %1, %2" : "=v"(r) : "v"(a), "v"(b));
    return r;
}

// ---------- pack QKVG weights (hi+lo) into MFMA A-fragment order ----------
// Apk[wid(8)][mf(4)][ks(4)][lane(64)][j(8)]; A[e][k] = W(e>>7)[e&127][k]
// wq pre-scaled by QSCALE*LOG2E (softmax in log2 domain).
__global__ __launch_bounds__(256)
void k_packw(const float* __restrict__ wq, const float* __restrict__ wk,
             const float* __restrict__ wv, const float* __restrict__ wg,
             bf16* __restrict__ Apkh, bf16* __restrict__ Apkl)
{
    const int idx = blockIdx.x * 256 + threadIdx.x;          // 0..65535
    const int j = idx & 7, lane = (idx >> 3) & 63;
    const int ks = (idx >> 9) & 3, mf = (idx >> 11) & 3, wid = idx >> 13;
    const int e = wid*64 + mf*16 + (lane & 15);
    const int k = ks*32 + (lane >> 4)*8 + j;
    const float* w = (e >> 7) == 0 ? wq : (e >> 7) == 1 ? wk : (e >> 7) == 2 ? wv : wg;
    float wv_ = w[(e & 127)*CZ + k];
    if (e < 128) wv_ *= QSCALE * LOG2E;
    const bf16 hb = tob(wv_);
    Apkh[idx] = hb;
    Apkl[idx] = tob(wv_ - __bfloat162float(hb));
}

// ---------- pack wo (hi+lo) B-side: [wn(2)][ks(4)][nr(4)][lane(64)][j(8)] ----------
__global__ __launch_bounds__(256)
void k_packwo(const float* __restrict__ wo, bf16* __restrict__ B2h,
              bf16* __restrict__ B2l)
{
    const int idx = blockIdx.x * 256 + threadIdx.x;          // 0..16383
    const int j = idx & 7, lane = (idx >> 3) & 63;
    const int nr = (idx >> 9) & 3, ks = (idx >> 11) & 3, wn = idx >> 13;
    const int n = wn*64 + nr*16 + (lane & 15);
    const int k = ks*32 + ((lane >> 4) << 3) + j;
    const float wv_ = wo[n*DM + k];
    const bf16 hb = tob(wv_);
    B2h[idx] = hb;
    B2l[idx] = tob(wv_ - __bfloat162float(hb));
}

// ---------- pack edge_bias -> bf16 per-lane fragment order, *LOG2E ----------
// ebpk[h][t(10)][w(5)][nf(4)][lane(64)][e(8)]; e = mi*4+r
// value = eb[h][q=64w+16nf+(lane&15)][k=32t+16mi+4*(lane>>4)+r]
__global__ __launch_bounds__(256)
void k_packeb(const float* __restrict__ eb, bf16* __restrict__ ebpk)
{
    const int idx = blockIdx.x * 256 + threadIdx.x;          // 0..409599
    const int e = idx & 7;
    const int lane = (idx >> 3) & 63;
    const int nf = (idx >> 9) & 3;
    const int w = (idx >> 11) % 5;
    const int t = (idx / 10240) % 10;
    const int h = idx / 102400;
    const int q = w*64 + nf*16 + (lane & 15);
    const int k = t*32 + (e >> 2)*16 + (lane >> 4)*4 + (e & 3);
    ebpk[idx] = tob(eb[((size_t)h*NRES + q)*NRES + k] * LOG2E);
}

// ---------- pre-scale mask_bias by LOG2E ----------
__global__ __launch_bounds__(256)
void k_packmb(const float* __restrict__ mb, float* __restrict__ mbpk)
{
    const int idx = blockIdx.x * 256 + threadIdx.x;          // 0..102399
    mbpk[idx] = mb[idx] * LOG2E;
}

// ---------- Kernel 1: LN + QKVG projection, split-bf16 MFMA (A=W, B=zn) ----------
// grid NPOS/64, block 512. Wave wid owns output e in [wid*64, wid*64+64), all 64 jj.
// LDS: slot-major, pitch 1040 B  (bank-quad = (slot+row)&7 -> 8 lanes/quad, optimal)
__global__ __launch_bounds__(512, 3)
void k_lnproj(const float* __restrict__ z, const float* __restrict__ ln_w,
              const float* __restrict__ ln_b, const bf16* __restrict__ Apkh,
              const bf16* __restrict__ Apkl,
              bf16* __restrict__ qws, bf16* __restrict__ kws,
              bf16* __restrict__ vtws, bf16* __restrict__ gows)
{
    __shared__ __align__(16) char Bsh[16 * 1040];   // zn_hi: [slot 16][row 64] 16B elems
    __shared__ __align__(16) char Bsl[16 * 1040];   // zn_lo
    const int tid = threadIdx.x;
    const int p0 = blockIdx.x * 64;
    const int lane = tid & 63, wid = tid >> 6;
    const int l15 = lane & 15, g = lane >> 4;

    // LayerNorm: thread (r = tid>>3, t = tid&7) handles cols 16t..16t+15
    {
        const int r = tid >> 3, t = tid & 7, c0 = t*16;
        const float* zp = z + (size_t)(p0 + r)*CZ + c0;
        float v[16];
        {
            float4 t0 = *(const float4*)(zp + 0);
            float4 t1 = *(const float4*)(zp + 4);
            float4 t2 = *(const float4*)(zp + 8);
            float4 t3 = *(const float4*)(zp + 12);
            v[0]=t0.x; v[1]=t0.y; v[2]=t0.z; v[3]=t0.w;
            v[4]=t1.x; v[5]=t1.y; v[6]=t1.z; v[7]=t1.w;
            v[8]=t2.x; v[9]=t2.y; v[10]=t2.z; v[11]=t2.w;
            v[12]=t3.x; v[13]=t3.y; v[14]=t3.z; v[15]=t3.w;
        }
        float s = 0.f, s2 = 0.f;
        #pragma unroll
        for (int c = 0; c < 16; ++c) { s += v[c]; s2 = fmaf(v[c], v[c], s2); }
        s  += __shfl_xor(s, 1);  s  += __shfl_xor(s, 2);  s  += __shfl_xor(s, 4);
        s2 += __shfl_xor(s2, 1); s2 += __shfl_xor(s2, 2); s2 += __shfl_xor(s2, 4);
        const float mu = s * 0.0078125f;
        const float rs = rsqrtf(s2 * 0.0078125f - mu*mu + LN_EPS);
        float vn[16];
        #pragma unroll
        for (int c = 0; c < 16; ++c)
            vn[c] = (v[c] - mu) * rs * ln_w[c0 + c] + ln_b[c0 + c];
        uint32_t hd[8], ld[8];
        #pragma unroll
        for (int c2 = 0; c2 < 8; ++c2) {
            hd[c2] = cvtpk(vn[2*c2], vn[2*c2+1]);
            ld[c2] = cvtpk(vn[2*c2]   - bflo(hd[c2]),
                           vn[2*c2+1] - bfhi(hd[c2]));
        }
        *(uint4*)(Bsh + (2*t    )*1040 + r*16) = make_uint4(hd[0], hd[1], hd[2], hd[3]);
        *(uint4*)(Bsh + (2*t + 1)*1040 + r*16) = make_uint4(hd[4], hd[5], hd[6], hd[7]);
        *(uint4*)(Bsl + (2*t    )*1040 + r*16) = make_uint4(ld[0], ld[1], ld[2], ld[3]);
        *(uint4*)(Bsl + (2*t + 1)*1040 + r*16) = make_uint4(ld[4], ld[5], ld[6], ld[7]);
    }
    __syncthreads();

    floatx4 acc[4][4];
    #pragma unroll
    for (int mf = 0; mf < 4; ++mf)
        #pragma unroll
        for (int nf = 0; nf < 4; ++nf)
            acc[mf][nf] = (floatx4){0.f, 0.f, 0.f, 0.f};

    const uint4* aph = (const uint4*)Apkh;
    const uint4* apl = (const uint4*)Apkl;
    #pragma unroll
    for (int ks = 0; ks < 4; ++ks) {
        uint4 ahv[4], alv[4];
        #pragma unroll
        for (int mf = 0; mf < 4; ++mf) {
            ahv[mf] = aph[((wid*4 + mf)*4 + ks)*64 + lane];
            alv[mf] = apl[((wid*4 + mf)*4 + ks)*64 + lane];
        }
        #pragma unroll
        for (int nf = 0; nf < 4; ++nf) {
            const int off = (ks*4 + g)*1040 + (16*nf + l15)*16;
            const short8 bh = *(const short8*)(Bsh + off);
            const short8 bl = *(const short8*)(Bsl + off);
            #pragma unroll
            for (int mf = 0; mf < 4; ++mf) {
                const short8 ah = *(const short8*)&ahv[mf];
                const short8 al = *(const short8*)&alv[mf];
                acc[mf][nf] = __builtin_amdgcn_mfma_f32_16x16x32_bf16(ah, bh, acc[mf][nf], 0, 0, 0);
                acc[mf][nf] = __builtin_amdgcn_mfma_f32_16x16x32_bf16(al, bh, acc[mf][nf], 0, 0, 0);
                acc[mf][nf] = __builtin_amdgcn_mfma_f32_16x16x32_bf16(ah, bl, acc[mf][nf], 0, 0, 0);
            }
        }
    }

    // epilogue: lane holds 4 consecutive c (e = e0..e0+3)
    const int i = p0 / NRES;          // blocks never straddle i
    const int j0 = p0 % NRES;
    #pragma unroll
    for (int mf = 0; mf < 4; ++mf) {
        const int e0 = wid*64 + mf*16 + 4*g;
        const int hh = (e0 >> 5) & 3, c0 = e0 & 31;
        #pragma unroll
        for (int nf = 0; nf < 4; ++nf) {
            const int jl = nf*16 + l15;
            const floatx4 a = acc[mf][nf];
            if (wid < 4) {           // q, k: row-major [i][h][jj][c]
                uint2 dw;
                dw.x = cvtpk(a[0], a[1]);
                dw.y = cvtpk(a[2], a[3]);
                bf16* dst = (wid < 2) ? qws : kws;
                const size_t hidx = ((size_t)((i*NH + hh)*NRES) + (j0 + jl))*CH + c0;
                *(uint2*)(dst + hidx) = dw;
            } else if (wid < 6) {    // v: transposed [i][h][c][jj]
                const size_t vbase = ((size_t)((i*NH + hh)*CH) + c0)*NRES + (j0 + jl);
                vtws[vbase         ] = tob(a[0]);
                vtws[vbase +   NRES] = tob(a[1]);
                vtws[vbase + 2*NRES] = tob(a[2]);
                vtws[vbase + 3*NRES] = tob(a[3]);
            } else {                 // gate
                const float g0 = 1.f / (1.f + __expf(-a[0]));
                const float g1 = 1.f / (1.f + __expf(-a[1]));
                const float g2 = 1.f / (1.f + __expf(-a[2]));
                const float g3 = 1.f / (1.f + __expf(-a[3]));
                uint2 dw;
                dw.x = cvtpk(g0, g1);
                dw.y = cvtpk(g2, g3);
                *(uint2*)(gows + (size_t)(p0 + jl)*DM + (e0 & 127)) = dw;
            }
        }
    }
}

// ---------------- Kernel 2: MFMA flash attention per (i, h) ----------------
// 5 waves x 64 q, 4 nf. Zero barriers; K/V/Q/eb/mb all direct from global (L2-hot).
// S^T = K·Q^T (softmax q lane-local); P via per-wave LDS round-trip (pitch 80 B);
// O^T = V^T·P^T. log2-domain softmax, defer-max.
__global__ __launch_bounds__(320, 3)
void k_attn(const bf16* __restrict__ qws, const bf16* __restrict__ kws,
            const bf16* __restrict__ vtws, bf16* __restrict__ gows,
            const float* __restrict__ mbpk, const bf16* __restrict__ ebpk)
{
    // per-wave P buffer: [64 q-rows][80 B]  (64 B of data = 32 k-bf16, 16 B pad)
    __shared__ __align__(16) char psmem[5 * 64 * 80];   // 25600 B
    const int i = blockIdx.x, h = blockIdx.y;
    const int tid = threadIdx.x;
    const int lane = tid & 63, w = tid >> 6;
    const int l15 = lane & 15, g = lane >> 4;
    const size_t slab = (size_t)(i*NH + h) * NRES * CH;
    char* psb = psmem + w*5120;

    const uint4* qg = (const uint4*)(qws + slab);
    const uint4* kg = (const uint4*)(kws + slab);
    const uint4* vg = (const uint4*)(vtws + slab);    // [c][k], row = 320 bf16
    const float* mbr = mbpk + (size_t)i*NRES;
    const uint4* ebp = (const uint4*)ebpk;
    const int ebbase = h*12800 + w*256 + lane;

    // Q B-frags
    short8 bq[4];
    #pragma unroll
    for (int nf = 0; nf < 4; ++nf) {
        uint4 t = qg[(64*w + 16*nf + l15)*4 + g];
        bq[nf] = *(short8*)&t;
    }
    // prologue: K frags + eb for t=0
    uint4 kc0 = kg[(     l15)*4 + g];
    uint4 kc1 = kg[(16 + l15)*4 + g];
    uint4 ebc[4];
    #pragma unroll
    for (int nf = 0; nf < 4; ++nf) ebc[nf] = ebp[ebbase + nf*64];

    floatx4 o[2][4];
    #pragma unroll
    for (int ma = 0; ma < 2; ++ma)
        #pragma unroll
        for (int nf = 0; nf < 4; ++nf)
            o[ma][nf] = (floatx4){0.f, 0.f, 0.f, 0.f};
    float m[4] = {-1e30f, -1e30f, -1e30f, -1e30f};
    float l[4] = {0.f, 0.f, 0.f, 0.f};

    for (int t = 0; t < 10; ++t) {
        // issue V frags + mask-bias for THIS tile (consumed late in the iter)
        uint4 av0u = vg[(     l15)*40 + 4*t + g];
        uint4 av1u = vg[(16 + l15)*40 + 4*t + g];
        float2 mbv[2][2];
        #pragma unroll
        for (int mi = 0; mi < 2; ++mi)
            #pragma unroll
            for (int rp = 0; rp < 2; ++rp)
                mbv[mi][rp] = *(const float2*)(mbr + 32*t + 16*mi + 4*g + 2*rp);

        // S^T = K·Q^T
        const short8 ak0 = *(short8*)&kc0;
        const short8 ak1 = *(short8*)&kc1;
        floatx4 sa[2][4];
        #pragma unroll
        for (int nf = 0; nf < 4; ++nf) {
            sa[0][nf] = __builtin_amdgcn_mfma_f32_16x16x32_bf16(ak0, bq[nf], (floatx4){0.f,0.f,0.f,0.f}, 0, 0, 0);
            sa[1][nf] = __builtin_amdgcn_mfma_f32_16x16x32_bf16(ak1, bq[nf], (floatx4){0.f,0.f,0.f,0.f}, 0, 0, 0);
        }
        // prefetch next tile's K + eb (critical-path inputs)
        const int tn = (t < 9) ? t + 1 : 9;
        uint4 kn0 = kg[(32*tn +      l15)*4 + g];
        uint4 kn1 = kg[(32*tn + 16 + l15)*4 + g];
        uint4 ebn[4];
        #pragma unroll
        for (int nf = 0; nf < 4; ++nf) ebn[nf] = ebp[ebbase + tn*1280 + nf*64];

        // s = S^T + eb + mb; lane-local max
        float sv[4][2][4];
        float lmax[4];
        #pragma unroll
        for (int nf = 0; nf < 4; ++nf) {
            const uint4 E = ebc[nf];
            sv[nf][0][0] = sa[0][nf][0] + (bflo(E.x) + mbv[0][0].x);
            sv[nf][0][1] = sa[0][nf][1] + (bfhi(E.x) + mbv[0][0].y);
            sv[nf][0][2] = sa[0][nf][2] + (bflo(E.y) + mbv[0][1].x);
            sv[nf][0][3] = sa[0][nf][3] + (bfhi(E.y) + mbv[0][1].y);
            sv[nf][1][0] = sa[1][nf][0] + (bflo(E.z) + mbv[1][0].x);
            sv[nf][1][1] = sa[1][nf][1] + (bfhi(E.z) + mbv[1][0].y);
            sv[nf][1][2] = sa[1][nf][2] + (bflo(E.w) + mbv[1][1].x);
            sv[nf][1][3] = sa[1][nf][3] + (bfhi(E.w) + mbv[1][1].y);
            const float a0 = fmaxf(fmaxf(sv[nf][0][0], sv[nf][0][1]), fmaxf(sv[nf][0][2], sv[nf][0][3]));
            const float a1 = fmaxf(fmaxf(sv[nf][1][0], sv[nf][1][1]), fmaxf(sv[nf][1][2], sv[nf][1][3]));
            lmax[nf] = fmaxf(a0, a1);
        }
        // defer-max (log2 domain): rescale only when needed
        const float gm = fmaxf(fmaxf(lmax[0] - m[0], lmax[1] - m[1]),
                               fmaxf(lmax[2] - m[2], lmax[3] - m[3]));
        if (__any(gm > 12.0f)) {
            #pragma unroll
            for (int nf = 0; nf < 4; ++nf) {
                float pm = lmax[nf];
                pm = fmaxf(pm, __shfl_xor(pm, 16));
                pm = fmaxf(pm, __shfl_xor(pm, 32));
                const float mn = fmaxf(m[nf], pm);
                const float sc = exp2f(m[nf] - mn);
                l[nf] *= sc;
                #pragma unroll
                for (int ma = 0; ma < 2; ++ma)
                    #pragma unroll
                    for (int r = 0; r < 4; ++r)
                        o[ma][nf][r] *= sc;
                m[nf] = mn;
            }
        }
        // p = 2^(s-m); write C-layout -> per-wave LDS (b64), read back as B-frags (b128)
        #pragma unroll
        for (int nf = 0; nf < 4; ++nf) {
            const int qrow = 16*nf + l15;
            #pragma unroll
            for (int mi = 0; mi < 2; ++mi) {
                const float p0 = exp2f(sv[nf][mi][0] - m[nf]);
                const float p1 = exp2f(sv[nf][mi][1] - m[nf]);
                const float p2 = exp2f(sv[nf][mi][2] - m[nf]);
                const float p3 = exp2f(sv[nf][mi][3] - m[nf]);
                l[nf] += (p0 + p1) + (p2 + p3);
                *(uint2*)(psb + qrow*80 + 32*mi + 8*g) =
                    make_uint2(cvtpk(p0, p1), cvtpk(p2, p3));
            }
        }
        const short8 av0 = *(short8*)&av0u;
        const short8 av1 = *(short8*)&av1u;
        #pragma unroll
        for (int nf = 0; nf < 4; ++nf) {
            const short8 bp = *(const short8*)(psb + (16*nf + l15)*80 + 16*g);
            o[0][nf] = __builtin_amdgcn_mfma_f32_16x16x32_bf16(av0, bp, o[0][nf], 0, 0, 0);
            o[1][nf] = __builtin_amdgcn_mfma_f32_16x16x32_bf16(av1, bp, o[1][nf], 0, 0, 0);
        }
        kc0 = kn0; kc1 = kn1;
        #pragma unroll
        for (int nf = 0; nf < 4; ++nf) ebc[nf] = ebn[nf];
    }

    // combine partial l across the 4 k-groups, then gate+store (b32 packed RMW)
    float linv[4];
    #pragma unroll
    for (int nf = 0; nf < 4; ++nf) {
        float ls = l[nf];
        ls += __shfl_xor(ls, 16);
        ls += __shfl_xor(ls, 32);
        linv[nf] = 1.f / ls;
    }
    uint32_t* gp = (uint32_t*)gows;
    #pragma unroll
    for (int nf = 0; nf < 4; ++nf) {
        const int jq = 64*w + 16*nf + l15;
        #pragma unroll
        for (int ma = 0; ma < 2; ++ma)
            #pragma unroll
            for (int rp = 0; rp < 2; ++rp) {
                const size_t idx = ((size_t)(i*NRES + jq))*64 + h*16 + 8*ma + 2*g + rp;
                const uint32_t u = gp[idx];
                const float v0 = o[ma][nf][2*rp    ] * linv[nf] * bflo(u);
                const float v1 = o[ma][nf][2*rp + 1] * linv[nf] * bfhi(u);
                gp[idx] = cvtpk(v0, v1);
            }
    }
}

// ---------- Kernel 3: output projection, MFMA (B split; A is bf16-exact) ----------
// LDS slot-major pitch 4112 B (bank-quad (slot+row)&7, optimal)
__global__ __launch_bounds__(512)
void k_outproj(const bf16* __restrict__ gows, const bf16* __restrict__ B2h,
               const bf16* __restrict__ B2l, float* __restrict__ out)
{
    __shared__ __align__(16) char As[16 * 4112];   // 65792 B: [slot 16][row 256] 16B
    const int tid = threadIdx.x;
    const int p0 = blockIdx.x * 256;
    const int lane = tid & 63, wid = tid >> 6;
    const int wm = wid >> 1, wn = wid & 1;

    short8 bh[4][4];
    {
        const uint4* bp = (const uint4*)B2h;
        #pragma unroll
        for (int ks = 0; ks < 4; ++ks)
            #pragma unroll
            for (int nr = 0; nr < 4; ++nr) {
                uint4 t = bp[(((wn*4 + ks)*4) + nr)*64 + lane];
                bh[ks][nr] = *(short8*)&t;
            }
    }

    {
        const uint4* src = (const uint4*)(gows + (size_t)p0 * DM);
        #pragma unroll
        for (int it = 0; it < 8; ++it) {
            const int t = tid + it*512;
            uint4 u = src[t];
            *(uint4*)(As + (t & 15)*4112 + (t >> 4)*16) = u;
        }
    }
    __syncthreads();

    floatx4 acc[4][4];
    #pragma unroll
    for (int m = 0; m < 4; ++m)
        #pragma unroll
        for (int n = 0; n < 4; ++n)
            acc[m][n] = (floatx4){0.f, 0.f, 0.f, 0.f};

    const uint4* bpl = (const uint4*)B2l;
    #pragma unroll
    for (int ks = 0; ks < 4; ++ks) {
        short8 a[4];
        #pragma unroll
        for (int m = 0; m < 4; ++m) {
            const int row = wm*64 + m*16 + (lane & 15);
            a[m] = *(const short8*)(As + (ks*4 + (lane >> 4))*4112 + row*16);
        }
        #pragma unroll
        for (int nr = 0; nr < 4; ++nr) {
            uint4 tl = bpl[(((wn*4 + ks)*4) + nr)*64 + lane];
            const short8 bl = *(short8*)&tl;
            #pragma unroll
            for (int m = 0; m < 4; ++m)
                acc[m][nr] = __builtin_amdgcn_mfma_f32_16x16x32_bf16(a[m], bh[ks][nr], acc[m][nr], 0, 0, 0);
            #pragma unroll
            for (int m = 0; m < 4; ++m)
                acc[m][nr] = __builtin_amdgcn_mfma_f32_16x16x32_bf16(a[m], bl, acc[m][nr], 0, 0, 0);
        }
    }

    #pragma unroll
    for (int m = 0; m < 4; ++m) {
        #pragma unroll
        for (int n = 0; n < 4; ++n) {
            const int d = wn*64 + n*16 + (lane & 15);
            #pragma unroll
            for (int r = 0; r < 4; ++r) {
                const int prow = p0 + wm*64 + m*16 + ((lane >> 4) << 2) + r;
                out[(size_t)prow*DM + d] = acc[m][n][r];
            }
        }
    }
}

extern "C" void kernel_launch(void* const* d_in, const int* in_sizes, int n_in,
                              void* d_out, int out_size, void* d_ws, size_t ws_size,
                              hipStream_t stream)
{
    const float* z   = (const float*)d_in[0];
    const float* mb  = (const float*)d_in[1];
    const float* eb  = (const float*)d_in[2];
    const float* wq  = (const float*)d_in[3];
    const float* wk  = (const float*)d_in[4];
    const float* wv  = (const float*)d_in[5];
    const float* wg  = (const float*)d_in[6];
    const float* wo  = (const float*)d_in[7];
    const float* lnw = (const float*)d_in[8];
    const float* lnb = (const float*)d_in[9];
    float* out = (float*)d_out;

    const size_t SEG = (size_t)NPOS * DM;
    bf16* qws  = (bf16*)d_ws;
    bf16* kws  = qws + SEG;
    bf16* vtws = kws + SEG;          // V transposed: [i][h][c][k]
    bf16* gows = vtws + SEG;
    bf16* Apkh = gows + SEG;         // 65536
    bf16* Apkl = Apkh + 65536;       // 65536
    bf16* B2h  = Apkl + 65536;       // 16384
    bf16* B2l  = B2h + 16384;        // 16384
    bf16* ebpk = B2l + 16384;        // 409600 bf16
    float* mbpk = (float*)(ebpk + 409600);   // 102400 f32

    k_packw<<<256, 256, 0, stream>>>(wq, wk, wv, wg, Apkh, Apkl);
    k_packwo<<<64, 256, 0, stream>>>(wo, B2h, B2l);
    k_packeb<<<1600, 256, 0, stream>>>(eb, ebpk);
    k_packmb<<<400, 256, 0, stream>>>(mb, mbpk);
    k_lnproj<<<NPOS/64, 512, 0, stream>>>(z, lnw, lnb, Apkh, Apkl, qws, kws, vtws, gows);
    k_attn<<<dim3(NRES, NH), 320, 0, stream>>>(qws, kws, vtws, gows, mbpk, ebpk);
    k_outproj<<<NPOS/256, 512, 0, stream>>>(gows, B2h, B2l, out);
}